// Round 1
// baseline (1310.647 us; speedup 1.0000x reference)
//
#include <hip/hip_runtime.h>
#include <math.h>

#define NTAG 96
#define BDIM 128   // forward-kernel block size (96 active columns + 32 barrier-only lanes)
#define NB   128   // batch
#define SLEN 2048  // sequence length

__device__ __forceinline__ float waveMax(float v) {
    #pragma unroll
    for (int o = 32; o > 0; o >>= 1) v = fmaxf(v, __shfl_xor(v, o));
    return v;
}
__device__ __forceinline__ float waveSum(float v) {
    #pragma unroll
    for (int o = 32; o > 0; o >>= 1) v += __shfl_xor(v, o);
    return v;
}

// block (128 threads = 2 waves) max reduction; uses sRed[2]; 2 internal barriers
__device__ __forceinline__ float blockMax2(float v, float* sRed, int tid) {
    v = waveMax(v);
    if ((tid & 63) == 0) sRed[tid >> 6] = v;
    __syncthreads();
    float r = fmaxf(sRed[0], sRed[1]);
    __syncthreads();
    return r;
}

// ---------------------------------------------------------------------------
// Forward algorithm (log partition), one workgroup per batch element.
// alpha kept in LINEAR domain (scaled), expT column kept in registers.
// ---------------------------------------------------------------------------
__global__ __launch_bounds__(BDIM) void crf_forward(
    const float* __restrict__ em,     // [B][S][96]
    const float* __restrict__ mask,   // [B][S]
    const float* __restrict__ trans,  // [96][96]
    const float* __restrict__ startT, // [96]
    const float* __restrict__ endT,   // [96]
    float* __restrict__ den)          // [B]
{
    __shared__ float sA[2][NTAG];   // double-buffered scaled-linear alpha
    __shared__ float sRed[2];
    __shared__ float sMask[SLEN];   // 8 KB: whole mask row

    const int b = blockIdx.x;
    const int tid = threadIdx.x;
    const int j = tid;
    const bool act = (j < NTAG);
    const float* emB = em + (size_t)b * SLEN * NTAG;

    for (int t = tid; t < SLEN; t += BDIM)
        sMask[t] = mask[(size_t)b * SLEN + t];

    // global max over transitions (uniform scale for expT)
    float tm = -1e30f;
    for (int k = tid; k < NTAG * NTAG; k += BDIM) tm = fmaxf(tm, trans[k]);
    tm = waveMax(tm);
    if ((tid & 63) == 0) sRed[tid >> 6] = tm;
    __syncthreads();
    const float tmax = fmaxf(sRed[0], sRed[1]);
    __syncthreads();

    // register-resident column j of expT: rT[i] = exp(trans[i][j] - tmax)
    float rT[NTAG];
    if (act) {
        #pragma unroll
        for (int i = 0; i < NTAG; ++i)
            rT[i] = __expf(trans[i * NTAG + j] - tmax);
    } else {
        #pragma unroll
        for (int i = 0; i < NTAG; ++i) rT[i] = 0.f;
    }

    // init: alpha0 = start + emissions[:,0]; convert to scaled linear
    float a0 = act ? (startT[j] + emB[j]) : -1e30f;
    float m0 = blockMax2(a0, sRed, tid);
    float logScale = m0;
    if (act) sA[0][j] = __expf(a0 - m0);
    __syncthreads();

    int cur = 0;
    // depth-2 emissions prefetch
    float emN0 = act ? emB[(size_t)1 * NTAG + j] : 0.f;
    float emN1 = act ? ((SLEN > 2) ? emB[(size_t)2 * NTAG + j] : 0.f) : 0.f;

    for (int t = 1; t < SLEN; ++t) {
        float emit = emN0;
        emN0 = emN1;
        if (act && (t + 2 < SLEN)) emN1 = emB[(size_t)(t + 2) * NTAG + j];
        const float mt = sMask[t];          // uniform across block
        if (mt != 0.f) {
            if (act) {
                float s0 = 0.f, s1 = 0.f, s2 = 0.f, s3 = 0.f;
                #pragma unroll
                for (int i = 0; i < NTAG; i += 8) {
                    float4 aA = *(const float4*)&sA[cur][i];
                    float4 aB = *(const float4*)&sA[cur][i + 4];
                    s0 = fmaf(aA.x, rT[i + 0], s0);
                    s1 = fmaf(aA.y, rT[i + 1], s1);
                    s2 = fmaf(aA.z, rT[i + 2], s2);
                    s3 = fmaf(aA.w, rT[i + 3], s3);
                    s0 = fmaf(aB.x, rT[i + 4], s0);
                    s1 = fmaf(aB.y, rT[i + 5], s1);
                    s2 = fmaf(aB.z, rT[i + 6], s2);
                    s3 = fmaf(aB.w, rT[i + 7], s3);
                }
                float na = ((s0 + s1) + (s2 + s3)) * __expf(emit);
                sA[cur ^ 1][j] = na;
            }
            cur ^= 1;
            logScale += tmax;
        }
        __syncthreads();

        // renormalize every 8 steps (exact max), keeps fp32 in range
        if ((t & 7) == 0) {
            float v = act ? sA[cur][j] : 0.f;
            float r = blockMax2(v, sRed, tid);
            if (act) sA[cur][j] = v * (1.0f / r);
            logScale += __logf(r);
            __syncthreads();
        }
    }

    // final: log_den = logScale + log(sum_j al[j] * exp(end[j]))
    float fv = act ? sA[cur][j] * __expf(endT[j]) : 0.f;
    fv = waveSum(fv);
    if ((tid & 63) == 0) sRed[tid >> 6] = fv;
    __syncthreads();
    if (tid == 0) den[b] = logScale + __logf(sRed[0] + sRed[1]);
}

// ---------------------------------------------------------------------------
// Gold-path score (log numerator), one workgroup per batch element.
// ---------------------------------------------------------------------------
__global__ __launch_bounds__(256) void crf_score(
    const float* __restrict__ em, const int* __restrict__ tags,
    const float* __restrict__ mask, const float* __restrict__ trans,
    const float* __restrict__ startT, const float* __restrict__ endT,
    float* __restrict__ num)
{
    __shared__ float sS[4], sM[4];
    const int b = blockIdx.x, tid = threadIdx.x;
    const float* emB = em + (size_t)b * SLEN * NTAG;
    const int* tgB = tags + (size_t)b * SLEN;
    const float* mkB = mask + (size_t)b * SLEN;

    float part = 0.f, mcnt = 0.f;
    for (int t = tid; t < SLEN; t += 256) {
        float mt = mkB[t];
        mcnt += mt;
        if (t >= 1) {
            int tp = tgB[t - 1], tc = tgB[t];
            part += (trans[tp * NTAG + tc] + emB[(size_t)t * NTAG + tc]) * mt;
        }
    }
    part = waveSum(part);
    mcnt = waveSum(mcnt);
    if ((tid & 63) == 0) { sS[tid >> 6] = part; sM[tid >> 6] = mcnt; }
    __syncthreads();
    if (tid == 0) {
        float tot = sS[0] + sS[1] + sS[2] + sS[3];
        int last = (int)(sM[0] + sM[1] + sM[2] + sM[3]) - 1;
        int t0 = tgB[0];
        num[b] = tot + startT[t0] + emB[t0] + endT[tgB[last]];
    }
}

// ---------------------------------------------------------------------------
// Final: out = mean_b(den[b] - num[b])
// ---------------------------------------------------------------------------
__global__ __launch_bounds__(128) void crf_final(
    const float* __restrict__ den, const float* __restrict__ num,
    float* __restrict__ out)
{
    __shared__ float s2[2];
    const int tid = threadIdx.x;
    float v = den[tid] - num[tid];
    v = waveSum(v);
    if ((tid & 63) == 0) s2[tid >> 6] = v;
    __syncthreads();
    if (tid == 0) out[0] = (s2[0] + s2[1]) * (1.0f / NB);
}

extern "C" void kernel_launch(void* const* d_in, const int* in_sizes, int n_in,
                              void* d_out, int out_size, void* d_ws, size_t ws_size,
                              hipStream_t stream) {
    const float* em     = (const float*)d_in[0];
    const int*   tags   = (const int*)d_in[1];
    const float* mask   = (const float*)d_in[2];
    const float* trans  = (const float*)d_in[3];
    const float* startT = (const float*)d_in[4];
    const float* endT   = (const float*)d_in[5];
    float* out = (float*)d_out;
    float* num = (float*)d_ws;        // [128]
    float* den = num + NB;            // [128]

    crf_score<<<NB, 256, 0, stream>>>(em, tags, mask, trans, startT, endT, num);
    crf_forward<<<NB, BDIM, 0, stream>>>(em, mask, trans, startT, endT, den);
    crf_final<<<1, 128, 0, stream>>>(den, num, out);
}

// Round 3
// 1138.588 us; speedup vs baseline: 1.1511x; 1.1511x over previous
//
#include <hip/hip_runtime.h>
#include <hip/hip_bf16.h>
#include <math.h>

#define NTAG 96
#define NB   128
#define SLEN 2048
#define CPERB (SLEN * NTAG)     // 196608 floats per batch row of em
#define TROWF (NTAG * NB)       // 12288 floats per t-row of eexpT
#define PADS  2056              // padded t-rows (8 extra for tail prefetch)

typedef __attribute__((ext_vector_type(8))) short bf16x8;
typedef __attribute__((ext_vector_type(4))) float f32x4;
union U8 { unsigned int u[4]; bf16x8 v; };

// pack two f32 -> one dword of two bf16 (RNE), lo = first. No inline asm:
// compiler lowers __float2bfloat16 pairs to v_cvt_pk_bf16_f32.
__device__ __forceinline__ unsigned int pk2bf(float lo, float hi) {
    union { __hip_bfloat16 h; unsigned short u; } a, b;
    a.h = __float2bfloat16(lo);
    b.h = __float2bfloat16(hi);
    return (unsigned int)a.u | ((unsigned int)b.u << 16);
}

__device__ __forceinline__ float waveSum(float v) {
    #pragma unroll
    for (int o = 32; o > 0; o >>= 1) v += __shfl_xor(v, o);
    return v;
}

// ---------------------------------------------------------------------------
// exp+transpose: eexpT[t][(j>>2)][b][(j&3)] = exp(em[b][t][j])
// one block: fixed t, 32 j's, 32 b's.  (CPERB/32 blocks x, NB/32 blocks y)
// ---------------------------------------------------------------------------
__global__ __launch_bounds__(256) void exp_transpose(
    const float* __restrict__ em, float* __restrict__ eexpT)
{
    __shared__ float tl[32][33];
    const int tid = threadIdx.x;
    const int tx = tid & 31, ty = tid >> 5;
    const int bx = blockIdx.x;
    const size_t c0 = (size_t)bx * 32;      // c = t*96 + j; 96 = 3*32 so one t per block
    const int t  = bx / 3;
    const int j0 = (bx % 3) * 32;
    const int b0 = blockIdx.y * 32;
    #pragma unroll
    for (int yy = 0; yy < 4; ++yy) {
        int bb = ty + 8 * yy;
        tl[bb][tx] = __expf(em[(size_t)(b0 + bb) * CPERB + c0 + tx]);
    }
    __syncthreads();
    // each thread writes one float4: j-group jg (4 consecutive j), batch bl
    const int jg = ty;   // 0..7
    const int bl = tx;   // 0..31
    f32x4 o;
    o[0] = tl[bl][4 * jg + 0];
    o[1] = tl[bl][4 * jg + 1];
    o[2] = tl[bl][4 * jg + 2];
    o[3] = tl[bl][4 * jg + 3];
    *(f32x4*)(eexpT + (size_t)t * TROWF + (size_t)(j0 / 4 + jg) * 64 + (size_t)(b0 + bl) * 4) = o;
}

__global__ __launch_bounds__(256) void mask_transpose(
    const float* __restrict__ mask, float* __restrict__ maskT)
{
    int idx = blockIdx.x * 256 + threadIdx.x;   // SLEN*NB total
    if (idx < SLEN * NB) {
        int t = idx >> 7, bb = idx & 127;
        maskT[idx] = mask[(size_t)bb * SLEN + t];
    }
}

// ---------------------------------------------------------------------------
// Forward algorithm: 1 wave = 16 batches. Scaled-linear domain, MFMA matvec.
// alpha relayout C->B goes through LDS (conflict-free padded layout),
// double-buffered, 1 syncthreads/step. No inline asm anywhere.
// PRE=1: srcE=eexpT (layout above), srcM=maskT[t][b]. PRE=0: raw em/mask.
// ---------------------------------------------------------------------------
template <int PRE>
__global__ __launch_bounds__(64, 1) void crf_forward_mm(
    const float* __restrict__ srcE, const float* __restrict__ srcM,
    const float* __restrict__ trans, const float* __restrict__ startT,
    const float* __restrict__ endT, float* __restrict__ den)
{
    __shared__ unsigned int lbuf[2][48 * 20];   // [pair q][b16], pad 20 => conflict-free
    const int tid = threadIdx.x;
    const int g = tid >> 4;       // 0..3
    const int b16 = tid & 15;
    const int b = blockIdx.x * 16 + b16;

    // global max of transitions (uniform scale)
    float tm = -1e30f;
    for (int k = tid; k < NTAG * NTAG; k += 64) tm = fmaxf(tm, trans[k]);
    #pragma unroll
    for (int o = 32; o > 0; o >>= 1) tm = fmaxf(tm, __shfl_xor(tm, o));
    const float tmax = tm;

    // constant A fragments: row j = 16*jt + b16, k-slot (g,e) -> i = 32*kf+8g+e
    bf16x8 Af[6][3];
    #pragma unroll
    for (int jt = 0; jt < 6; ++jt) {
        #pragma unroll
        for (int kf = 0; kf < 3; ++kf) {
            U8 u;
            #pragma unroll
            for (int d = 0; d < 4; ++d) {
                int i0 = 32 * kf + 8 * g + 2 * d;
                int j = 16 * jt + b16;
                u.u[d] = pk2bf(__expf(trans[i0 * NTAG + j] - tmax),
                               __expf(trans[(i0 + 1) * NTAG + j] - tmax));
            }
            Af[jt][kf] = u.v;
        }
    }

    // init alpha (scaled linear): slot tile*4+r holds (j = 16*tile+4g+r, b)
    float alphaF[24];
    #pragma unroll
    for (int tile = 0; tile < 6; ++tile) {
        #pragma unroll
        for (int r = 0; r < 4; ++r) {
            int j = 16 * tile + 4 * g + r;
            float e0;
            if (PRE) e0 = srcE[(size_t)(j >> 2) * 64 + b * 4 + (j & 3)];
            else     e0 = __expf(srcE[(size_t)b * CPERB + j]);
            alphaF[tile * 4 + r] = __expf(startT[j]) * e0;
        }
    }
    float ls = 0.0f;

#define RENORM() do { \
    float mx_ = alphaF[0]; \
    _Pragma("unroll") \
    for (int k_ = 1; k_ < 24; ++k_) mx_ = fmaxf(mx_, alphaF[k_]); \
    mx_ = fmaxf(mx_, __shfl_xor(mx_, 16)); \
    mx_ = fmaxf(mx_, __shfl_xor(mx_, 32)); \
    float inv_ = 1.0f / mx_; \
    ls += __logf(mx_); \
    _Pragma("unroll") \
    for (int k_ = 0; k_ < 24; ++k_) alphaF[k_] *= inv_; \
} while (0)

    // pack alpha pairs -> LDS -> read back as B fragments.
    // writer: pair q = 8*tile + 2*g (+1), value = (alpha[2q], alpha[2q+1])
    // reader: Bu[kf].u[d] = pair q = 16*kf + 4*g + d
    U8 Bu[3];
#define MAKEB(BUF) do { \
    _Pragma("unroll") \
    for (int t_ = 0; t_ < 6; ++t_) { \
        lbuf[BUF][(8 * t_ + 2 * g) * 20 + b16]     = pk2bf(alphaF[4 * t_ + 0], alphaF[4 * t_ + 1]); \
        lbuf[BUF][(8 * t_ + 2 * g + 1) * 20 + b16] = pk2bf(alphaF[4 * t_ + 2], alphaF[4 * t_ + 3]); \
    } \
    __syncthreads(); \
    _Pragma("unroll") \
    for (int kf_ = 0; kf_ < 3; ++kf_) { \
        _Pragma("unroll") \
        for (int d_ = 0; d_ < 4; ++d_) \
            Bu[kf_].u[d_] = lbuf[BUF][(16 * kf_ + 4 * g + d_) * 20 + b16]; \
    } \
} while (0)

    // emission prefetch ring, depth 8 (E[tile][r] as f32x4; constant indices only)
    f32x4 E[8][6];
    float Mr[8];

#define LOADE(P, T) do { \
    int tl_ = (T); \
    if (!PRE && tl_ > SLEN - 1) tl_ = SLEN - 1; \
    if (PRE) { \
        const f32x4* pE_ = (const f32x4*)(srcE + (size_t)tl_ * TROWF); \
        _Pragma("unroll") \
        for (int t_ = 0; t_ < 6; ++t_) \
            E[P][t_] = pE_[(4 * t_ + g) * 16 + b16]; \
        Mr[P] = srcM[tl_ * NB + b]; \
    } else { \
        _Pragma("unroll") \
        for (int t_ = 0; t_ < 6; ++t_) \
            E[P][t_] = *(const f32x4*)(srcE + (size_t)b * CPERB + tl_ * NTAG + 16 * t_ + 4 * g); \
        Mr[P] = srcM[(size_t)b * SLEN + tl_]; \
    } \
} while (0)

    LOADE(0, 1); LOADE(1, 2); LOADE(2, 3); LOADE(3, 4);
    LOADE(4, 5); LOADE(5, 6); LOADE(6, 7); LOADE(7, 8);

    const f32x4 zf4 = {0.f, 0.f, 0.f, 0.f};

#define STEP(P, TCUR) do { \
    f32x4 acc_[6]; \
    _Pragma("unroll") \
    for (int jt_ = 0; jt_ < 6; ++jt_) { \
        f32x4 a_ = __builtin_amdgcn_mfma_f32_16x16x32_bf16(Af[jt_][0], Bu[0].v, zf4, 0, 0, 0); \
        a_ = __builtin_amdgcn_mfma_f32_16x16x32_bf16(Af[jt_][1], Bu[1].v, a_, 0, 0, 0); \
        a_ = __builtin_amdgcn_mfma_f32_16x16x32_bf16(Af[jt_][2], Bu[2].v, a_, 0, 0, 0); \
        acc_[jt_] = a_; \
    } \
    float mv_ = Mr[P]; \
    unsigned long long bal_ = __ballot(mv_ != 0.0f); \
    if (bal_ == ~0ull) { \
        _Pragma("unroll") \
        for (int t_ = 0; t_ < 6; ++t_) { \
            _Pragma("unroll") \
            for (int r_ = 0; r_ < 4; ++r_) { \
                float x_ = PRE ? E[P][t_][r_] : __expf(E[P][t_][r_]); \
                alphaF[t_ * 4 + r_] = acc_[t_][r_] * x_; \
            } \
        } \
        ls += tmax; \
    } else { \
        bool km_ = (mv_ != 0.0f); \
        _Pragma("unroll") \
        for (int t_ = 0; t_ < 6; ++t_) { \
            _Pragma("unroll") \
            for (int r_ = 0; r_ < 4; ++r_) { \
                float x_ = PRE ? E[P][t_][r_] : __expf(E[P][t_][r_]); \
                float nv_ = acc_[t_][r_] * x_; \
                alphaF[t_ * 4 + r_] = km_ ? nv_ : alphaF[t_ * 4 + r_]; \
            } \
        } \
        ls += km_ ? tmax : 0.0f; \
    } \
    LOADE(P, (TCUR) + 8); \
} while (0)

    RENORM();
    MAKEB(1);

    int tB = 1;
    #pragma unroll 1
    for (int blk = 0; blk < 255; ++blk, tB += 8) {
        STEP(0, tB + 0);           MAKEB(0);
        STEP(1, tB + 1);           MAKEB(1);
        STEP(2, tB + 2);           MAKEB(0);
        STEP(3, tB + 3); RENORM(); MAKEB(1);
        STEP(4, tB + 4);           MAKEB(0);
        STEP(5, tB + 5);           MAKEB(1);
        STEP(6, tB + 6);           MAKEB(0);
        STEP(7, tB + 7); RENORM(); MAKEB(1);
    }
    // tail: t = 2041..2047 (ring holds them; trailing loads hit pad rows, dead)
    STEP(0, 2041);           MAKEB(0);
    STEP(1, 2042);           MAKEB(1);
    STEP(2, 2043);           MAKEB(0);
    STEP(3, 2044); RENORM(); MAKEB(1);
    STEP(4, 2045);           MAKEB(0);
    STEP(5, 2046);           MAKEB(1);
    STEP(6, 2047);

    // log_den[b] = ls + log(sum_j alpha[j] * exp(end_j))
    float s = 0.f;
    #pragma unroll
    for (int tile = 0; tile < 6; ++tile) {
        #pragma unroll
        for (int r = 0; r < 4; ++r) {
            int j = 16 * tile + 4 * g + r;
            s += alphaF[tile * 4 + r] * __expf(endT[j]);
        }
    }
    s += __shfl_xor(s, 16);
    s += __shfl_xor(s, 32);
    if (tid < 16) den[b] = ls + __logf(s);
#undef STEP
#undef LOADE
#undef MAKEB
#undef RENORM
}

// ---------------------------------------------------------------------------
// Gold-path score (R1-verified, unchanged)
// ---------------------------------------------------------------------------
__global__ __launch_bounds__(256) void crf_score(
    const float* __restrict__ em, const int* __restrict__ tags,
    const float* __restrict__ mask, const float* __restrict__ trans,
    const float* __restrict__ startT, const float* __restrict__ endT,
    float* __restrict__ num)
{
    __shared__ float sS[4], sM[4];
    const int b = blockIdx.x, tid = threadIdx.x;
    const float* emB = em + (size_t)b * CPERB;
    const int* tgB = tags + (size_t)b * SLEN;
    const float* mkB = mask + (size_t)b * SLEN;

    float part = 0.f, mcnt = 0.f;
    for (int t = tid; t < SLEN; t += 256) {
        float mt = mkB[t];
        mcnt += mt;
        if (t >= 1) {
            int tp = tgB[t - 1], tc = tgB[t];
            part += (trans[tp * NTAG + tc] + emB[(size_t)t * NTAG + tc]) * mt;
        }
    }
    part = waveSum(part);
    mcnt = waveSum(mcnt);
    if ((tid & 63) == 0) { sS[tid >> 6] = part; sM[tid >> 6] = mcnt; }
    __syncthreads();
    if (tid == 0) {
        float tot = sS[0] + sS[1] + sS[2] + sS[3];
        int last = (int)(sM[0] + sM[1] + sM[2] + sM[3]) - 1;
        int t0 = tgB[0];
        num[b] = tot + startT[t0] + emB[t0] + endT[tgB[last]];
    }
}

__global__ __launch_bounds__(128) void crf_final(
    const float* __restrict__ den, const float* __restrict__ num,
    float* __restrict__ out)
{
    __shared__ float s2[2];
    const int tid = threadIdx.x;
    float v = den[tid] - num[tid];
    v = waveSum(v);
    if ((tid & 63) == 0) s2[tid >> 6] = v;
    __syncthreads();
    if (tid == 0) out[0] = (s2[0] + s2[1]) * (1.0f / NB);
}

extern "C" void kernel_launch(void* const* d_in, const int* in_sizes, int n_in,
                              void* d_out, int out_size, void* d_ws, size_t ws_size,
                              hipStream_t stream) {
    const float* em     = (const float*)d_in[0];
    const int*   tags   = (const int*)d_in[1];
    const float* mask   = (const float*)d_in[2];
    const float* trans  = (const float*)d_in[3];
    const float* startT = (const float*)d_in[4];
    const float* endT   = (const float*)d_in[5];
    float* out = (float*)d_out;
    float* num = (float*)d_ws;                    // [128]
    float* den = num + NB;                        // [128]
    float* eexpT = (float*)((char*)d_ws + 4096);  // [PADS][24][128][4] floats
    float* maskT = eexpT + (size_t)PADS * TROWF;  // [PADS][128]
    size_t need = 4096 + (size_t)PADS * TROWF * 4 + (size_t)PADS * NB * 4;

    crf_score<<<NB, 256, 0, stream>>>(em, tags, mask, trans, startT, endT, num);
    if (ws_size >= need) {
        exp_transpose<<<dim3(CPERB / 32, NB / 32), 256, 0, stream>>>(em, eexpT);
        mask_transpose<<<(SLEN * NB) / 256, 256, 0, stream>>>(mask, maskT);
        crf_forward_mm<1><<<NB / 16, 64, 0, stream>>>(eexpT, maskT, trans, startT, endT, den);
    } else {
        crf_forward_mm<0><<<NB / 16, 64, 0, stream>>>(em, mask, trans, startT, endT, den);
    }
    crf_final<<<1, 128, 0, stream>>>(den, num, out);
}

// Round 4
// 744.054 us; speedup vs baseline: 1.7615x; 1.5302x over previous
//
#include <hip/hip_runtime.h>
#include <hip/hip_bf16.h>
#include <math.h>

#define NTAG 96
#define NB   128
#define SLEN 2048
#define CPERB (SLEN * NTAG)     // floats per batch row of em
#define NCH  8                  // chunks per sequence
#define CHUNK 256               // steps per chunk (last chunk: 255)

typedef __attribute__((ext_vector_type(8))) short bf16x8;
typedef __attribute__((ext_vector_type(4))) float f32x4;
union U8 { unsigned int u[4]; bf16x8 v; };

__device__ __forceinline__ unsigned int pk2bf(float lo, float hi) {
    union { __hip_bfloat16 h; unsigned short u; } a, b;
    a.h = __float2bfloat16(lo);
    b.h = __float2bfloat16(hi);
    return (unsigned int)a.u | ((unsigned int)b.u << 16);
}

__device__ __forceinline__ float waveSum(float v) {
    #pragma unroll
    for (int o = 32; o > 0; o >>= 1) v += __shfl_xor(v, o);
    return v;
}

// ---------------------------------------------------------------------------
// Phase 1: per (batch, chunk, strip) wave computes a 96x16 column-strip of
// the chunk operator product  M <- diag(e_t) * T^T * M,  M init = Identity.
// Machinery identical to R3's verified kernel (Af frags, MAKEB transpose,
// per-column renorm). Output: P[bc][i][j] (fp32) + per-column log-scale Pls.
// ---------------------------------------------------------------------------
__global__ __launch_bounds__(64, 2) void crf_chunk(
    const float* __restrict__ em, const float* __restrict__ mask,
    const float* __restrict__ trans,
    float* __restrict__ P, float* __restrict__ Pls)
{
    __shared__ unsigned int lbuf[48 * 20];   // single buffer (1 wave, in-order DS)
    const int tid = threadIdx.x;
    const int g = tid >> 4, b16 = tid & 15;
    const int wid = blockIdx.x;              // [0, 6*1024)
    const int w  = wid >> 10;                // strip 0..5 (columns 16w..16w+15)
    const int bc = wid & 1023;               // b*NCH + c
    const int c  = bc & (NCH - 1);
    const int b  = bc >> 3;
    const int t0 = 1 + c * CHUNK;
    const int t1 = min(SLEN, t0 + CHUNK);

    // global max of transitions (uniform scale)
    float tm = -1e30f;
    for (int k = tid; k < NTAG * NTAG; k += 64) tm = fmaxf(tm, trans[k]);
    #pragma unroll
    for (int o = 32; o > 0; o >>= 1) tm = fmaxf(tm, __shfl_xor(tm, o));
    const float tmax = tm;

    // constant A fragments = Texp^T: row j = 16*jt + b16, k i = 32*kf+8g+e
    bf16x8 Af[6][3];
    #pragma unroll
    for (int jt = 0; jt < 6; ++jt) {
        #pragma unroll
        for (int kf = 0; kf < 3; ++kf) {
            U8 u;
            #pragma unroll
            for (int d = 0; d < 4; ++d) {
                int i0 = 32 * kf + 8 * g + 2 * d;
                int j = 16 * jt + b16;
                u.u[d] = pk2bf(__expf(trans[i0 * NTAG + j] - tmax),
                               __expf(trans[(i0 + 1) * NTAG + j] - tmax));
            }
            Af[jt][kf] = u.v;
        }
    }

    // M init = identity column strip: slot tile*4+r holds (row j=16*tile+4g+r,
    // col i = 16*w + b16): 1 if j == i else 0.
    float alphaF[24];
    #pragma unroll
    for (int tile = 0; tile < 6; ++tile) {
        #pragma unroll
        for (int r = 0; r < 4; ++r)
            alphaF[tile * 4 + r] = (16 * tile + 4 * g + r == 16 * w + b16) ? 1.0f : 0.0f;
    }
    float ls = 0.0f;

#define RENORM() do { \
    float mx_ = alphaF[0]; \
    _Pragma("unroll") \
    for (int k_ = 1; k_ < 24; ++k_) mx_ = fmaxf(mx_, alphaF[k_]); \
    mx_ = fmaxf(mx_, __shfl_xor(mx_, 16)); \
    mx_ = fmaxf(mx_, __shfl_xor(mx_, 32)); \
    mx_ = fmaxf(mx_, 1e-30f); \
    float inv_ = 1.0f / mx_; \
    ls += __logf(mx_); \
    _Pragma("unroll") \
    for (int k_ = 0; k_ < 24; ++k_) alphaF[k_] *= inv_; \
} while (0)

    U8 Bu[3];
#define MAKEB() do { \
    _Pragma("unroll") \
    for (int t_ = 0; t_ < 6; ++t_) { \
        lbuf[(8 * t_ + 2 * g) * 20 + b16]     = pk2bf(alphaF[4 * t_ + 0], alphaF[4 * t_ + 1]); \
        lbuf[(8 * t_ + 2 * g + 1) * 20 + b16] = pk2bf(alphaF[4 * t_ + 2], alphaF[4 * t_ + 3]); \
    } \
    __syncthreads(); \
    _Pragma("unroll") \
    for (int kf_ = 0; kf_ < 3; ++kf_) { \
        _Pragma("unroll") \
        for (int d_ = 0; d_ < 4; ++d_) \
            Bu[kf_].u[d_] = lbuf[(16 * kf_ + 4 * g + d_) * 20 + b16]; \
    } \
    __syncthreads(); \
} while (0)

    MAKEB();

    const float* emB = em + (size_t)b * CPERB;
    const float* mkB = mask + (size_t)b * SLEN;
    const f32x4 zf4 = {0.f, 0.f, 0.f, 0.f};

    #pragma unroll 1
    for (int t = t0; t < t1; ++t) {
        // emission row (broadcast within 16-lane groups); loaded early so the
        // MFMA block below hides its latency
        f32x4 E[6];
        #pragma unroll
        for (int tl = 0; tl < 6; ++tl)
            E[tl] = *(const f32x4*)(emB + (size_t)t * NTAG + 16 * tl + 4 * g);
        float mv = mkB[t];   // wave-uniform

        f32x4 acc[6];
        #pragma unroll
        for (int jt = 0; jt < 6; ++jt) {
            f32x4 a_ = __builtin_amdgcn_mfma_f32_16x16x32_bf16(Af[jt][0], Bu[0].v, zf4, 0, 0, 0);
            a_ = __builtin_amdgcn_mfma_f32_16x16x32_bf16(Af[jt][1], Bu[1].v, a_, 0, 0, 0);
            a_ = __builtin_amdgcn_mfma_f32_16x16x32_bf16(Af[jt][2], Bu[2].v, a_, 0, 0, 0);
            acc[jt] = a_;
        }

        if (mv != 0.0f) {
            #pragma unroll
            for (int tile = 0; tile < 6; ++tile) {
                #pragma unroll
                for (int r = 0; r < 4; ++r)
                    alphaF[tile * 4 + r] = acc[tile][r] * __expf(E[tile][r]);
            }
            ls += tmax;
        }
        if (((t - t0) & 3) == 3) RENORM();
        MAKEB();
    }

    // store: P[bc][i = 16w+b16][j] fp32, Pls[bc][i] per-column log-scale
    float* Pb = P + ((size_t)bc * NTAG + (16 * w + b16)) * NTAG + 4 * g;
    #pragma unroll
    for (int tile = 0; tile < 6; ++tile) {
        f32x4 v;
        v[0] = alphaF[4 * tile + 0]; v[1] = alphaF[4 * tile + 1];
        v[2] = alphaF[4 * tile + 2]; v[3] = alphaF[4 * tile + 3];
        *(f32x4*)(Pb + 16 * tile) = v;
    }
    if (tid < 16) Pls[(size_t)bc * NTAG + 16 * w + b16] = ls;
#undef MAKEB
#undef RENORM
}

// ---------------------------------------------------------------------------
// Phase 2: per-batch log-domain fold of the NCH chunk operators.
// A'[j] = m + log( sum_i exp(A[i]+s_c[i]-m) * Mhat_c[i][j] )
// ---------------------------------------------------------------------------
__global__ __launch_bounds__(128) void crf_fold(
    const float* __restrict__ em, const float* __restrict__ startT,
    const float* __restrict__ endT,
    const float* __restrict__ P, const float* __restrict__ Pls,
    float* __restrict__ den)
{
    __shared__ float aS[NTAG];
    __shared__ float sRed[2];
    const int b = blockIdx.x, tid = threadIdx.x;
    const bool act = tid < NTAG;

    float A = act ? (startT[tid] + em[(size_t)b * CPERB + tid]) : -1e30f;

    for (int c = 0; c < NCH; ++c) {
        const size_t bc = (size_t)b * NCH + c;
        float v = act ? (A + Pls[bc * NTAG + tid]) : -1e30f;
        // block max (2 waves)
        float mv = v;
        #pragma unroll
        for (int o = 32; o > 0; o >>= 1) mv = fmaxf(mv, __shfl_xor(mv, o));
        if ((tid & 63) == 0) sRed[tid >> 6] = mv;
        __syncthreads();
        const float m = fmaxf(sRed[0], sRed[1]);
        __syncthreads();
        if (act) aS[tid] = __expf(v - m);
        __syncthreads();
        if (act) {
            const float* Pc = P + bc * (NTAG * NTAG) + tid;
            float dot = 0.f;
            #pragma unroll 8
            for (int i = 0; i < NTAG; ++i)
                dot = fmaf(aS[i], Pc[(size_t)i * NTAG], dot);
            A = m + __logf(dot);
        }
        __syncthreads();
    }

    float Af = act ? (A + endT[tid]) : -1e30f;
    float mv = Af;
    #pragma unroll
    for (int o = 32; o > 0; o >>= 1) mv = fmaxf(mv, __shfl_xor(mv, o));
    if ((tid & 63) == 0) sRed[tid >> 6] = mv;
    __syncthreads();
    const float m2 = fmaxf(sRed[0], sRed[1]);
    __syncthreads();
    float ex = act ? __expf(Af - m2) : 0.f;
    ex = waveSum(ex);
    if ((tid & 63) == 0) sRed[tid >> 6] = ex;
    __syncthreads();
    if (tid == 0) den[b] = m2 + __logf(sRed[0] + sRed[1]);
}

// ---------------------------------------------------------------------------
// Fallback sequential forward (R3-verified path, raw inputs) — used only if
// the workspace were too small for P.
// ---------------------------------------------------------------------------
__global__ __launch_bounds__(64, 1) void crf_forward_seq(
    const float* __restrict__ srcE, const float* __restrict__ srcM,
    const float* __restrict__ trans, const float* __restrict__ startT,
    const float* __restrict__ endT, float* __restrict__ den)
{
    __shared__ unsigned int lbuf[2][48 * 20];
    const int tid = threadIdx.x;
    const int g = tid >> 4;
    const int b16 = tid & 15;
    const int b = blockIdx.x * 16 + b16;

    float tm = -1e30f;
    for (int k = tid; k < NTAG * NTAG; k += 64) tm = fmaxf(tm, trans[k]);
    #pragma unroll
    for (int o = 32; o > 0; o >>= 1) tm = fmaxf(tm, __shfl_xor(tm, o));
    const float tmax = tm;

    bf16x8 Af[6][3];
    #pragma unroll
    for (int jt = 0; jt < 6; ++jt) {
        #pragma unroll
        for (int kf = 0; kf < 3; ++kf) {
            U8 u;
            #pragma unroll
            for (int d = 0; d < 4; ++d) {
                int i0 = 32 * kf + 8 * g + 2 * d;
                int j = 16 * jt + b16;
                u.u[d] = pk2bf(__expf(trans[i0 * NTAG + j] - tmax),
                               __expf(trans[(i0 + 1) * NTAG + j] - tmax));
            }
            Af[jt][kf] = u.v;
        }
    }

    float alphaF[24];
    #pragma unroll
    for (int tile = 0; tile < 6; ++tile) {
        #pragma unroll
        for (int r = 0; r < 4; ++r) {
            int j = 16 * tile + 4 * g + r;
            alphaF[tile * 4 + r] = __expf(startT[j]) * __expf(srcE[(size_t)b * CPERB + j]);
        }
    }
    float ls = 0.0f;

#define RENORM2() do { \
    float mx_ = alphaF[0]; \
    _Pragma("unroll") \
    for (int k_ = 1; k_ < 24; ++k_) mx_ = fmaxf(mx_, alphaF[k_]); \
    mx_ = fmaxf(mx_, __shfl_xor(mx_, 16)); \
    mx_ = fmaxf(mx_, __shfl_xor(mx_, 32)); \
    mx_ = fmaxf(mx_, 1e-30f); \
    float inv_ = 1.0f / mx_; \
    ls += __logf(mx_); \
    _Pragma("unroll") \
    for (int k_ = 0; k_ < 24; ++k_) alphaF[k_] *= inv_; \
} while (0)

    U8 Bu[3];
#define MAKEB2(BUF) do { \
    _Pragma("unroll") \
    for (int t_ = 0; t_ < 6; ++t_) { \
        lbuf[BUF][(8 * t_ + 2 * g) * 20 + b16]     = pk2bf(alphaF[4 * t_ + 0], alphaF[4 * t_ + 1]); \
        lbuf[BUF][(8 * t_ + 2 * g + 1) * 20 + b16] = pk2bf(alphaF[4 * t_ + 2], alphaF[4 * t_ + 3]); \
    } \
    __syncthreads(); \
    _Pragma("unroll") \
    for (int kf_ = 0; kf_ < 3; ++kf_) { \
        _Pragma("unroll") \
        for (int d_ = 0; d_ < 4; ++d_) \
            Bu[kf_].u[d_] = lbuf[BUF][(16 * kf_ + 4 * g + d_) * 20 + b16]; \
    } \
} while (0)

    RENORM2();
    MAKEB2(0);
    const f32x4 zf4 = {0.f, 0.f, 0.f, 0.f};

    #pragma unroll 1
    for (int t = 1; t < SLEN; ++t) {
        f32x4 E[6];
        #pragma unroll
        for (int tl = 0; tl < 6; ++tl)
            E[tl] = *(const f32x4*)(srcE + (size_t)b * CPERB + (size_t)t * NTAG + 16 * tl + 4 * g);
        float mv = srcM[(size_t)b * SLEN + t];
        f32x4 acc[6];
        #pragma unroll
        for (int jt = 0; jt < 6; ++jt) {
            f32x4 a_ = __builtin_amdgcn_mfma_f32_16x16x32_bf16(Af[jt][0], Bu[0].v, zf4, 0, 0, 0);
            a_ = __builtin_amdgcn_mfma_f32_16x16x32_bf16(Af[jt][1], Bu[1].v, a_, 0, 0, 0);
            a_ = __builtin_amdgcn_mfma_f32_16x16x32_bf16(Af[jt][2], Bu[2].v, a_, 0, 0, 0);
            acc[jt] = a_;
        }
        bool km = (mv != 0.0f);
        #pragma unroll
        for (int tile = 0; tile < 6; ++tile) {
            #pragma unroll
            for (int r = 0; r < 4; ++r) {
                float nv = acc[tile][r] * __expf(E[tile][r]);
                alphaF[tile * 4 + r] = km ? nv : alphaF[tile * 4 + r];
            }
        }
        ls += km ? tmax : 0.0f;
        if ((t & 3) == 0) RENORM2();
        MAKEB2(t & 1);
        __syncthreads();
    }

    float s = 0.f;
    #pragma unroll
    for (int tile = 0; tile < 6; ++tile) {
        #pragma unroll
        for (int r = 0; r < 4; ++r) {
            int j = 16 * tile + 4 * g + r;
            s += alphaF[tile * 4 + r] * __expf(endT[j]);
        }
    }
    s += __shfl_xor(s, 16);
    s += __shfl_xor(s, 32);
    if (tid < 16) den[b] = ls + __logf(s);
#undef MAKEB2
#undef RENORM2
}

// ---------------------------------------------------------------------------
// Gold-path score (verified, unchanged)
// ---------------------------------------------------------------------------
__global__ __launch_bounds__(256) void crf_score(
    const float* __restrict__ em, const int* __restrict__ tags,
    const float* __restrict__ mask, const float* __restrict__ trans,
    const float* __restrict__ startT, const float* __restrict__ endT,
    float* __restrict__ num)
{
    __shared__ float sS[4], sM[4];
    const int b = blockIdx.x, tid = threadIdx.x;
    const float* emB = em + (size_t)b * CPERB;
    const int* tgB = tags + (size_t)b * SLEN;
    const float* mkB = mask + (size_t)b * SLEN;

    float part = 0.f, mcnt = 0.f;
    for (int t = tid; t < SLEN; t += 256) {
        float mt = mkB[t];
        mcnt += mt;
        if (t >= 1) {
            int tp = tgB[t - 1], tc = tgB[t];
            part += (trans[tp * NTAG + tc] + emB[(size_t)t * NTAG + tc]) * mt;
        }
    }
    part = waveSum(part);
    mcnt = waveSum(mcnt);
    if ((tid & 63) == 0) { sS[tid >> 6] = part; sM[tid >> 6] = mcnt; }
    __syncthreads();
    if (tid == 0) {
        float tot = sS[0] + sS[1] + sS[2] + sS[3];
        int last = (int)(sM[0] + sM[1] + sM[2] + sM[3]) - 1;
        int t0 = tgB[0];
        num[b] = tot + startT[t0] + emB[t0] + endT[tgB[last]];
    }
}

__global__ __launch_bounds__(128) void crf_final(
    const float* __restrict__ den, const float* __restrict__ num,
    float* __restrict__ out)
{
    __shared__ float s2[2];
    const int tid = threadIdx.x;
    float v = den[tid] - num[tid];
    v = waveSum(v);
    if ((tid & 63) == 0) s2[tid >> 6] = v;
    __syncthreads();
    if (tid == 0) out[0] = (s2[0] + s2[1]) * (1.0f / NB);
}

extern "C" void kernel_launch(void* const* d_in, const int* in_sizes, int n_in,
                              void* d_out, int out_size, void* d_ws, size_t ws_size,
                              hipStream_t stream) {
    const float* em     = (const float*)d_in[0];
    const int*   tags   = (const int*)d_in[1];
    const float* mask   = (const float*)d_in[2];
    const float* trans  = (const float*)d_in[3];
    const float* startT = (const float*)d_in[4];
    const float* endT   = (const float*)d_in[5];
    float* out = (float*)d_out;
    float* num = (float*)d_ws;                    // [128]
    float* den = num + NB;                        // [128]
    float* P   = (float*)((char*)d_ws + 4096);    // [NB*NCH][96][96] fp32
    float* Pls = P + (size_t)NB * NCH * NTAG * NTAG;  // [NB*NCH][96]
    size_t need = 4096 + (size_t)NB * NCH * NTAG * NTAG * 4 + (size_t)NB * NCH * NTAG * 4;

    crf_score<<<NB, 256, 0, stream>>>(em, tags, mask, trans, startT, endT, num);
    if (ws_size >= need) {
        crf_chunk<<<6 * NB * NCH, 64, 0, stream>>>(em, mask, trans, P, Pls);
        crf_fold<<<NB, 128, 0, stream>>>(em, startT, endT, P, Pls, den);
    } else {
        crf_forward_seq<<<NB / 16, 64, 0, stream>>>(em, mask, trans, startT, endT, den);
    }
    crf_final<<<1, 128, 0, stream>>>(den, num, out);
}